// Round 16
// baseline (188.370 us; speedup 1.0000x reference)
//
#include <hip/hip_runtime.h>
#include <hip/hip_bf16.h>

#define T_SEQ 1024
#define D_MOD 512
#define NHEAD 8
#define HDIM  64
#define R_DIM 512
#define BATCH 2

typedef __attribute__((ext_vector_type(8))) __bf16 bf16x8;
typedef __attribute__((ext_vector_type(4))) __bf16 bf16x4;
typedef __attribute__((ext_vector_type(4))) float f32x4;

// runtime-dtype load/store: bf==1 -> bf16, bf==0 -> fp32 (wave-uniform branch)
__device__ __forceinline__ float ldin(const void* p, size_t i, int bf) {
    if (bf) return __bfloat162float(((const __hip_bfloat16*)p)[i]);
    return ((const float*)p)[i];
}
__device__ __forceinline__ void stout(void* p, size_t i, int bf, float v) {
    if (bf) ((__hip_bfloat16*)p)[i] = __float2bfloat16(v);
    else    ((float*)p)[i] = v;
}

__device__ __forceinline__ float gelu_f(float x) {
    return 0.5f * x * (1.f + tanhf(0.7978845608028654f * (x + 0.044715f * x * x * x)));
}

__device__ __forceinline__ bf16x8 cvt8(float4 a, float4 b) {
    bf16x8 t;
    t[0]=(__bf16)a.x; t[1]=(__bf16)a.y; t[2]=(__bf16)a.z; t[3]=(__bf16)a.w;
    t[4]=(__bf16)b.x; t[5]=(__bf16)b.y; t[6]=(__bf16)b.z; t[7]=(__bf16)b.w;
    return t;
}

// Inline dtype sniff: fp32 N(0,1) data has ~0.4% of 16-bit halves matching the
// bf16 inf/nan exponent; bf16 data has none. Deterministic & block-uniform.
__device__ __forceinline__ int detect_bf(const void* x) {
    __shared__ int cnt;
    if (threadIdx.x == 0) cnt = 0;
    __syncthreads();
    const unsigned short* h = (const unsigned short*)x;
    int c = 0;
    for (int i = threadIdx.x; i < 8192; i += 256)
        if ((h[i] & 0x7F80u) == 0x7F80u) c++;
    if (c) atomicAdd(&cnt, c);
    __syncthreads();
    return cnt == 0;
}

// ---------------- fused projection GEMMs + zero job (R11-measured version) ----
// 64x64 tile, BK=32, single LDS buffer (10.25 KB): measured 45-48 us.
// BK=64 (R12), 128-tile (R8), gather-staging (R9), pipelining (R10) all
// regressed -- this shape is the plateau. Cooperative single-kernel fusion
// (R14) fails under graph capture. Do not restructure.
__global__ __launch_bounds__(256) void mega_gemm(
    const void* __restrict__ x, const void* __restrict__ Mi,
    const void* __restrict__ stf, const void* __restrict__ Mf,
    const void* __restrict__ Wq, const void* __restrict__ bq,
    const void* __restrict__ Wk, const void* __restrict__ bk,
    const void* __restrict__ Wv, const void* __restrict__ bv,
    const void* __restrict__ Wg, const void* __restrict__ bg,
    __bf16* __restrict__ fu, __bf16* __restrict__ fphi,
    __bf16* __restrict__ fQ, __bf16* __restrict__ fKT,
    __bf16* __restrict__ fV, __bf16* __restrict__ fG)
{
    const int tid = threadIdx.x;
    const int job = blockIdx.z;
    if (job == 6) {
        float4* zp = (float4*)(fphi + 524288);          // fw..fY, 8 MB
        const int bid = blockIdx.y * 8 + blockIdx.x;    // 0..255, 32 KB each
        const float4 z4 = make_float4(0.f, 0.f, 0.f, 0.f);
        #pragma unroll
        for (int q = 0; q < 8; ++q)
            zp[(size_t)bid * 2048 + q * 256 + tid] = z4;
        return;
    }
    const int bf = detect_bf(x);
    const void* A = x; const void* Bw; const void* bias = nullptr;
    int Kd = 512, act = 0; bool trb = true;
    switch (job) {
        case 0: Bw = Mi; trb = false; break;
        case 1: Bw = Wq; bias = bq; act = 1; break;
        case 2: Bw = Wk; bias = bk; act = 1; break;
        case 3: Bw = Wv; bias = bv; act = 1; break;
        case 4: Bw = Wg; bias = bg; act = 2; break;
        default: A = stf; Bw = Mf; trb = false; Kd = 32; break;
    }
    const int M = (job == 5) ? 1024 : 2048;
    const int m0 = blockIdx.y * 64;
    if (m0 >= M) return;
    const int n0 = blockIdx.x * 64;

    __shared__ __align__(16) __bf16 As[64][40];
    __shared__ __align__(16) __bf16 Bs[64][40];
    const int wave = tid >> 6, lane = tid & 63;
    const int lm = lane & 15, kq = lane >> 4;

    f32x4 acc[4] = {};

    for (int k0 = 0; k0 < Kd; k0 += 32) {
        if (k0) __syncthreads();
        {
            const int mo = tid >> 2;
            const int ko = (tid & 3) * 8;
            if (job == 5) {
                #pragma unroll
                for (int q = 0; q < 8; ++q) {
                    const int k = ko + q;
                    As[mo][k] = (k < 24) ? (__bf16)ldin(A, (size_t)(m0 + mo) * 24 + k, bf)
                                         : (__bf16)0.f;
                }
            } else if (bf) {
                *(bf16x8*)&As[mo][ko] =
                    *(const bf16x8*)((const __bf16*)A + (size_t)(m0 + mo) * 512 + k0 + ko);
            } else {
                const float* Af = (const float*)A + (size_t)(m0 + mo) * 512 + k0 + ko;
                *(bf16x8*)&As[mo][ko] = cvt8(*(const float4*)Af, *(const float4*)(Af + 4));
            }
        }
        if (trb) {
            const int no = tid >> 2;
            const int ko = (tid & 3) * 8;
            const size_t go = (size_t)(n0 + no) * 512 + k0 + ko;
            if (bf) {
                *(bf16x8*)&Bs[no][ko] = *(const bf16x8*)((const __bf16*)Bw + go);
            } else {
                const float* Bf = (const float*)Bw + go;
                *(bf16x8*)&Bs[no][ko] = cvt8(*(const float4*)Bf, *(const float4*)(Bf + 4));
            }
        } else {
            const int kk = tid >> 3;            // 0..31
            const int nn = (tid & 7) * 8;
            if (job == 5) {
                #pragma unroll
                for (int q = 0; q < 8; ++q)
                    Bs[nn + q][kk] = (kk < 24) ? (__bf16)ldin(Bw, (size_t)kk * 512 + n0 + nn + q, bf)
                                               : (__bf16)0.f;
            } else {
                const size_t off = (size_t)(k0 + kk) * 512 + n0 + nn;
                if (bf) {
                    const bf16x8 t = *(const bf16x8*)((const __bf16*)Bw + off);
                    #pragma unroll
                    for (int q = 0; q < 8; ++q) Bs[nn + q][kk] = t[q];
                } else {
                    const float* Bf = (const float*)Bw + off;
                    #pragma unroll
                    for (int q = 0; q < 8; ++q) Bs[nn + q][kk] = (__bf16)Bf[q];
                }
            }
        }
        __syncthreads();
        const bf16x8 a = *(const bf16x8*)&As[wave * 16 + lm][kq * 8];
        #pragma unroll
        for (int nt = 0; nt < 4; ++nt) {
            const bf16x8 b = *(const bf16x8*)&Bs[nt * 16 + lm][kq * 8];
            acc[nt] = __builtin_amdgcn_mfma_f32_16x16x32_bf16(a, b, acc[nt], 0, 0, 0);
        }
    }
    // epilogue: D[m][n]: m = wave*16 + kq*4 + r2, n = nt*16 + lm
    #pragma unroll
    for (int nt = 0; nt < 4; ++nt) {
        const int n = n0 + nt * 16 + lm;
        #pragma unroll
        for (int r2 = 0; r2 < 4; ++r2) {
            const int m = m0 + wave * 16 + kq * 4 + r2;
            float v = acc[nt][r2];
            if (bias) v += ldin(bias, (size_t)n, bf);
            if (act == 1) v = gelu_f(v);
            if (act == 2) v = 1.f / (1.f + expf(-v));
            switch (job) {
                case 0: fu[(size_t)m * 512 + n] = (__bf16)v; break;
                case 5: fphi[(size_t)m * 512 + n] = (__bf16)v; break;
                case 1: fQ[(size_t)m * 512 + n] = (__bf16)v; break;
                case 3: fV[(size_t)m * 512 + n] = (__bf16)v; break;
                case 4: fG[(size_t)m * 512 + n] = (__bf16)v; break;
                case 2: {  // K transposed: [b][h][p][t]
                    const int b = m >> 10, t = m & 1023;
                    const int h = n >> 6,  p = n & 63;
                    fKT[(((size_t)b * NHEAD + h) * 64 + p) * T_SEQ + t] = (__bf16)v;
                    break;
                }
            }
        }
    }
}

// ---------------- fused uniform-task conv + attention, 4 j-tiles per block ----
// u/vphi bf16 (half staged global traffic), converted to fp32 at LDS staging.
__global__ __launch_bounds__(256) void conv_attn_k(
    const __bf16* __restrict__ u, const __bf16* __restrict__ vphi,
    float* __restrict__ w,
    const __bf16* __restrict__ Q, const __bf16* __restrict__ KT,
    const __bf16* __restrict__ V, float* __restrict__ Y)
{
    __shared__ __align__(16) unsigned char smem[49152];
    const int tid = threadIdx.x;
    const int z = blockIdx.z;
    int rem = blockIdx.x, ti = 0;
    while (rem >= ((ti + 4) >> 2)) { rem -= (ti + 4) >> 2; ++ti; }
    const int jlo = rem * 4;
    const int jhi = (jlo + 3 < ti) ? jlo + 3 : ti;
    const int t0 = ti * 64;

    if (z < 2) {
        float (*vs)[64] = (float (*)[64])smem;            // 16 KB
        float (*us)[64] = (float (*)[64])(smem + 16384);  // 32 KB
        const int rl = tid & 63, tg = tid >> 6;
        const int b = z;
        const int r0 = blockIdx.y * 64;
        const __bf16* ub = u + (size_t)b * T_SEQ * R_DIM;
        float acc[16] = {};
        for (int j = jlo; j <= jhi; ++j) {
            if (j != jlo) __syncthreads();
            const int L0 = j * 64;
            const int W0 = t0 - L0 - 63;
            #pragma unroll
            for (int jj = 0; jj < 8; ++jj) {
                const int n = jj * 256 + tid;
                const int row = n >> 4, c4 = (n & 15) * 4;
                int s = W0 + row;
                s = s < 0 ? 0 : (s > T_SEQ - 1 ? T_SEQ - 1 : s);
                const bf16x4 t = *(const bf16x4*)&ub[(size_t)s * R_DIM + r0 + c4];
                *(float4*)&us[row][c4] =
                    make_float4((float)t[0], (float)t[1], (float)t[2], (float)t[3]);
            }
            #pragma unroll
            for (int jj = 0; jj < 4; ++jj) {
                const int n = jj * 256 + tid;
                const int row = n >> 4, c4 = (n & 15) * 4;
                const bf16x4 t = *(const bf16x4*)&vphi[(size_t)(L0 + row) * R_DIM + r0 + c4];
                *(float4*)&vs[row][c4] =
                    make_float4((float)t[0], (float)t[1], (float)t[2], (float)t[3]);
            }
            __syncthreads();
            if (j < ti) {
                #pragma unroll
                for (int g = 0; g < 4; ++g) {
                    const int wsmin = tg * 16 + 49 - 16 * g;
                    float ur[30];
                    #pragma unroll
                    for (int q = 0; q < 30; ++q) ur[q] = us[wsmin + q][rl];
                    float vr[8];
                    #pragma unroll
                    for (int e = 0; e < 8; ++e) vr[e] = vs[16 * g + 2 * e][rl];
                    #pragma unroll
                    for (int e = 0; e < 8; ++e)
                        #pragma unroll
                        for (int i = 0; i < 16; ++i)
                            acc[i] += vr[e] * ur[i - 2 * e + 14];
                }
            } else {
                for (int l = 0; l < 64; l += 2) {
                    const float vv = vs[l][rl];
                    #pragma unroll
                    for (int i = 0; i < 16; ++i) {
                        const int srel = tg * 16 + i - l;
                        if (srel >= 0) acc[i] += vv * us[srel + 63][rl];
                    }
                }
            }
        }
        #pragma unroll
        for (int i = 0; i < 16; ++i)
            atomicAdd(&w[((size_t)b * T_SEQ + t0 + tg * 16 + i) * R_DIM + r0 + rl],
                      2.f * acc[i]);
    } else {
        __bf16 (*Qs)[72] = (__bf16 (*)[72])smem;
        __bf16 (*Vs)[72] = (__bf16 (*)[72])(smem + 9216);
        __bf16 (*Kt)[72] = (__bf16 (*)[72])(smem + 18432);
        __bf16 (*Sa)[72] = (__bf16 (*)[72])(smem + 27648);
        const int wave = tid >> 6, lane = tid & 63;
        const int lm = lane & 15, kq = lane >> 4;
        const int b = z - 2;
        const int h = blockIdx.y;
        const size_t cbase = ((size_t)b * T_SEQ) * D_MOD + h * HDIM;
        const __bf16* KTh = KT + (((size_t)b * NHEAD + h) * 64) * T_SEQ;
        #pragma unroll
        for (int it = 0; it < 2; ++it) {
            const int n = it * 256 + tid;
            const int row = n >> 3, p0 = (n & 7) * 8;
            *(bf16x8*)&Qs[row][p0] = *(const bf16x8*)&Q[cbase + (size_t)(t0 + row) * D_MOD + p0];
        }
        f32x4 accY[4] = {};
        for (int j = jlo; j <= jhi; ++j) {
            const int s0 = j * 64;
            __syncthreads();
            #pragma unroll
            for (int it = 0; it < 2; ++it) {
                const int n = it * 256 + tid;
                const int row = n >> 3, c0 = (n & 7) * 8;
                *(bf16x8*)&Vs[row][c0] = *(const bf16x8*)&V[cbase + (size_t)(s0 + row) * D_MOD + c0];
                *(bf16x8*)&Kt[row][c0] = *(const bf16x8*)&KTh[(size_t)row * T_SEQ + s0 + c0];
            }
            __syncthreads();
            f32x4 sacc[4] = {};
            #pragma unroll
            for (int ks = 0; ks < 2; ++ks) {
                const bf16x8 a = *(const bf16x8*)&Qs[wave * 16 + lm][ks * 32 + kq * 8];
                #pragma unroll
                for (int nt = 0; nt < 4; ++nt) {
                    const bf16x8 bb = *(const bf16x8*)&Vs[nt * 16 + lm][ks * 32 + kq * 8];
                    sacc[nt] = __builtin_amdgcn_mfma_f32_16x16x32_bf16(a, bb, sacc[nt], 0, 0, 0);
                }
            }
            const bool diag = (j == ti);
            #pragma unroll
            for (int nt = 0; nt < 4; ++nt) {
                const int sl = nt * 16 + lm;
                #pragma unroll
                for (int r2 = 0; r2 < 4; ++r2) {
                    const int tl = wave * 16 + kq * 4 + r2;
                    float v = sacc[nt][r2];
                    if (diag && sl > tl) v = 0.f;
                    Sa[tl][sl] = (__bf16)v;
                }
            }
            #pragma unroll
            for (int ks = 0; ks < 2; ++ks) {
                const bf16x8 a = *(const bf16x8*)&Sa[wave * 16 + lm][ks * 32 + kq * 8];
                #pragma unroll
                for (int nt = 0; nt < 4; ++nt) {
                    const bf16x8 bb = *(const bf16x8*)&Kt[nt * 16 + lm][ks * 32 + kq * 8];
                    accY[nt] = __builtin_amdgcn_mfma_f32_16x16x32_bf16(a, bb, accY[nt], 0, 0, 0);
                }
            }
        }
        #pragma unroll
        for (int nt = 0; nt < 4; ++nt) {
            const int nh = nt * 16 + lm;
            #pragma unroll
            for (int r2 = 0; r2 < 4; ++r2) {
                const int tl = wave * 16 + kq * 4 + r2;
                atomicAdd(&Y[cbase + (size_t)(t0 + tl) * D_MOD + nh], accY[nt][r2]);
            }
        }
    }
}

// layernorm over last dim (512): reads fp32 conv accum, writes BF16 x_tilde
__global__ __launch_bounds__(256) void ln_k(const float* __restrict__ w,
                                            __bf16* __restrict__ xt,
                                            const void* __restrict__ g,
                                            const void* __restrict__ b,
                                            const void* __restrict__ xref)
{
    const int bf = detect_bf(xref);
    const size_t row = (size_t)blockIdx.y * T_SEQ + blockIdx.x;
    const float* p = w + row * R_DIM;
    const int tid = threadIdx.x;
    const float x0 = p[tid], x1 = p[tid + 256];
    __shared__ float red[4];
    float s = x0 + x1;
    #pragma unroll
    for (int off = 32; off > 0; off >>= 1) s += __shfl_down(s, off, 64);
    if ((tid & 63) == 0) red[tid >> 6] = s;
    __syncthreads();
    const float mu = (red[0] + red[1] + red[2] + red[3]) * (1.f / 512.f);
    __syncthreads();
    const float d0 = x0 - mu, d1 = x1 - mu;
    float vsum = d0 * d0 + d1 * d1;
    #pragma unroll
    for (int off = 32; off > 0; off >>= 1) vsum += __shfl_down(vsum, off, 64);
    if ((tid & 63) == 0) red[tid >> 6] = vsum;
    __syncthreads();
    const float var = (red[0] + red[1] + red[2] + red[3]) * (1.f / 512.f);
    const float rs = rsqrtf(var + 1e-5f);
    __bf16* q = xt + row * R_DIM;
    q[tid]       = (__bf16)(d0 * rs * ldin(g, tid, bf)       + ldin(b, tid, bf));
    q[tid + 256] = (__bf16)(d1 * rs * ldin(g, tid + 256, bf) + ldin(b, tid + 256, bf));
}

// ---------------- final GEMM with fused comb: out = (g*y+(1-g)*xt) @ Wo^T + bo
// 32x64 tiles -> 512 blocks (2/CU, was 256 = 1/CU latency-exposed).
// Single LDS buffer 7.7 KB, mega-style staging. Wave w: rows (w&1)*16,
// cols (w>>1)*32 (2 MFMA tiles).
__global__ __launch_bounds__(256) void final_gemm(const __bf16* __restrict__ G,
                                                  const float* __restrict__ Yf,
                                                  const __bf16* __restrict__ Xt,
                                                  const void* __restrict__ Wo,
                                                  const void* __restrict__ bo,
                                                  void* __restrict__ out,
                                                  const void* __restrict__ xref)
{
    const int bf = detect_bf(xref);
    __shared__ __align__(16) __bf16 As[32][40];
    __shared__ __align__(16) __bf16 Bs[64][40];
    const int tid = threadIdx.x;
    const int wave = tid >> 6, lane = tid & 63;
    const int lm = lane & 15, kq = lane >> 4;
    const int m0 = blockIdx.y * 32, n0 = blockIdx.x * 64;
    const int mw = (wave & 1) * 16, nw = (wave >> 1) * 32;

    f32x4 acc[2] = {};

    for (int k0 = 0; k0 < 512; k0 += 32) {
        if (k0) __syncthreads();
        // stage A (comb fusion): 32 rows x 32 halves, threads 0..127
        if (tid < 128) {
            const int mo = tid >> 2;
            const int ko = (tid & 3) * 8;
            const size_t off = (size_t)(m0 + mo) * 512 + k0 + ko;
            const bf16x8 g8 = *(const bf16x8*)(G + off);
            const bf16x8 x8 = *(const bf16x8*)(Xt + off);
            const float4 y0 = *(const float4*)(Yf + off);
            const float4 y1 = *(const float4*)(Yf + off + 4);
            const float yv[8] = {y0.x,y0.y,y0.z,y0.w,y1.x,y1.y,y1.z,y1.w};
            bf16x8 t;
            #pragma unroll
            for (int q = 0; q < 8; ++q) {
                const float gg = (float)g8[q];
                t[q] = (__bf16)(gg * yv[q] + (1.f - gg) * (float)x8[q]);
            }
            *(bf16x8*)&As[mo][ko] = t;
        }
        // stage B: 64 rows x 32 halves, all 256 threads
        {
            const int no = tid >> 2;
            const int ko = (tid & 3) * 8;
            const size_t ob = (size_t)(n0 + no) * 512 + k0 + ko;
            if (bf) {
                *(bf16x8*)&Bs[no][ko] = *(const bf16x8*)((const __bf16*)Wo + ob);
            } else {
                const float* Bf = (const float*)Wo + ob;
                *(bf16x8*)&Bs[no][ko] = cvt8(*(const float4*)Bf, *(const float4*)(Bf + 4));
            }
        }
        __syncthreads();
        const bf16x8 a = *(const bf16x8*)&As[mw + lm][kq * 8];
        #pragma unroll
        for (int nt = 0; nt < 2; ++nt) {
            const bf16x8 b = *(const bf16x8*)&Bs[nw + nt * 16 + lm][kq * 8];
            acc[nt] = __builtin_amdgcn_mfma_f32_16x16x32_bf16(a, b, acc[nt], 0, 0, 0);
        }
    }
    #pragma unroll
    for (int nt = 0; nt < 2; ++nt) {
        const int n = n0 + nw + nt * 16 + lm;
        #pragma unroll
        for (int r2 = 0; r2 < 4; ++r2) {
            const int m = m0 + mw + kq * 4 + r2;
            float v = acc[nt][r2] + ldin(bo, (size_t)n, bf);
            stout(out, (size_t)m * 512 + n, bf, v);
        }
    }
}

extern "C" void kernel_launch(void* const* d_in, const int* in_sizes, int n_in,
                              void* d_out, int out_size, void* d_ws, size_t ws_size,
                              hipStream_t stream)
{
    const void* x   = d_in[0];
    const void* stf = d_in[1];
    const void* Mi  = d_in[2];
    const void* Mf  = d_in[3];
    const void* Wq  = d_in[4];  const void* bq = d_in[5];
    const void* Wk  = d_in[6];  const void* bk = d_in[7];
    const void* Wv  = d_in[8];  const void* bv = d_in[9];
    const void* Wg  = d_in[10]; const void* bg = d_in[11];
    const void* Wo  = d_in[12]; const void* bo = d_in[13];
    const void* lnw = d_in[14]; const void* lnb = d_in[15];

    float* base = (float*)d_ws;
    __bf16* f_u   = (__bf16*)base;               // u bf16 (2 MB)
    __bf16* f_phi = f_u + 1048576;               // phi bf16 (1 MB)
    float*  f_w   = base + 786432;               // conv accum fp32 (4 MB, zeroed)
    float*  f_Y   = base + 1835008;              // attn accum fp32 (4 MB, zeroed)
    __bf16* f_xt  = (__bf16*)(base + 2883584);   // x_tilde bf16 (2 MB)
    __bf16* f_Q   = (__bf16*)(base + 3407872);   // bf16 2048x512 (2 MB)
    __bf16* f_KT  = f_Q + 1048576;               // bf16 K transposed [b][h][p][t]
    __bf16* f_V   = f_KT + 1048576;
    __bf16* f_G   = f_V + 1048576;
    // total ws: 21 MB

    dim3 blk(256);

    // jobs 0-5 GEMMs (64x64, BK=32), job 6 zeroes f_w+f_Y (8 MB)
    mega_gemm<<<dim3(8, 32, 7), blk, 0, stream>>>(
        x, Mi, stf, Mf, Wq, bq, Wk, bk, Wv, bv, Wg, bg,
        f_u, f_phi, f_Q, f_KT, f_V, f_G);

    conv_attn_k<<<dim3(40, 8, 4), blk, 0, stream>>>(f_u, f_phi, f_w, f_Q, f_KT, f_V, f_Y);

    ln_k<<<dim3(T_SEQ, BATCH), blk, 0, stream>>>(f_w, f_xt, lnw, lnb, x);

    final_gemm<<<dim3(8, 64), blk, 0, stream>>>(f_G, f_Y, f_xt, Wo, bo, d_out, x);
}

// Round 17
// 183.741 us; speedup vs baseline: 1.0252x; 1.0252x over previous
//
#include <hip/hip_runtime.h>
#include <hip/hip_bf16.h>

#define T_SEQ 1024
#define D_MOD 512
#define NHEAD 8
#define HDIM  64
#define R_DIM 512
#define BATCH 2

typedef __attribute__((ext_vector_type(8))) __bf16 bf16x8;
typedef __attribute__((ext_vector_type(4))) __bf16 bf16x4;
typedef __attribute__((ext_vector_type(4))) float f32x4;

// runtime-dtype load/store: bf==1 -> bf16, bf==0 -> fp32 (wave-uniform branch)
__device__ __forceinline__ float ldin(const void* p, size_t i, int bf) {
    if (bf) return __bfloat162float(((const __hip_bfloat16*)p)[i]);
    return ((const float*)p)[i];
}
__device__ __forceinline__ void stout(void* p, size_t i, int bf, float v) {
    if (bf) ((__hip_bfloat16*)p)[i] = __float2bfloat16(v);
    else    ((float*)p)[i] = v;
}

__device__ __forceinline__ float gelu_f(float x) {
    return 0.5f * x * (1.f + tanhf(0.7978845608028654f * (x + 0.044715f * x * x * x)));
}

__device__ __forceinline__ bf16x8 cvt8(float4 a, float4 b) {
    bf16x8 t;
    t[0]=(__bf16)a.x; t[1]=(__bf16)a.y; t[2]=(__bf16)a.z; t[3]=(__bf16)a.w;
    t[4]=(__bf16)b.x; t[5]=(__bf16)b.y; t[6]=(__bf16)b.z; t[7]=(__bf16)b.w;
    return t;
}

// Inline dtype sniff: fp32 N(0,1) data has ~0.4% of 16-bit halves matching the
// bf16 inf/nan exponent; bf16 data has none. Deterministic & block-uniform.
__device__ __forceinline__ int detect_bf(const void* x) {
    __shared__ int cnt;
    if (threadIdx.x == 0) cnt = 0;
    __syncthreads();
    const unsigned short* h = (const unsigned short*)x;
    int c = 0;
    for (int i = threadIdx.x; i < 8192; i += 256)
        if ((h[i] & 0x7F80u) == 0x7F80u) c++;
    if (c) atomicAdd(&cnt, c);
    __syncthreads();
    return cnt == 0;
}

// ---------------- fused projection GEMMs + zero job (R11-measured version) ----
// 64x64 tile, BK=32, single LDS buffer (10.25 KB): measured 45-48 us.
// BK=64 (R12), 128-tile (R8), gather-staging (R9), pipelining (R10) all
// regressed -- this shape is the plateau. Cooperative single-kernel fusion
// (R14) fails under graph capture. Do not restructure.
__global__ __launch_bounds__(256) void mega_gemm(
    const void* __restrict__ x, const void* __restrict__ Mi,
    const void* __restrict__ stf, const void* __restrict__ Mf,
    const void* __restrict__ Wq, const void* __restrict__ bq,
    const void* __restrict__ Wk, const void* __restrict__ bk,
    const void* __restrict__ Wv, const void* __restrict__ bv,
    const void* __restrict__ Wg, const void* __restrict__ bg,
    __bf16* __restrict__ fu, __bf16* __restrict__ fphi,
    __bf16* __restrict__ fQ, __bf16* __restrict__ fKT,
    __bf16* __restrict__ fV, __bf16* __restrict__ fG)
{
    const int tid = threadIdx.x;
    const int job = blockIdx.z;
    if (job == 6) {
        float4* zp = (float4*)(fphi + 524288);          // fw..fY, 8 MB
        const int bid = blockIdx.y * 8 + blockIdx.x;    // 0..255, 32 KB each
        const float4 z4 = make_float4(0.f, 0.f, 0.f, 0.f);
        #pragma unroll
        for (int q = 0; q < 8; ++q)
            zp[(size_t)bid * 2048 + q * 256 + tid] = z4;
        return;
    }
    const int bf = detect_bf(x);
    const void* A = x; const void* Bw; const void* bias = nullptr;
    int Kd = 512, act = 0; bool trb = true;
    switch (job) {
        case 0: Bw = Mi; trb = false; break;
        case 1: Bw = Wq; bias = bq; act = 1; break;
        case 2: Bw = Wk; bias = bk; act = 1; break;
        case 3: Bw = Wv; bias = bv; act = 1; break;
        case 4: Bw = Wg; bias = bg; act = 2; break;
        default: A = stf; Bw = Mf; trb = false; Kd = 32; break;
    }
    const int M = (job == 5) ? 1024 : 2048;
    const int m0 = blockIdx.y * 64;
    if (m0 >= M) return;
    const int n0 = blockIdx.x * 64;

    __shared__ __align__(16) __bf16 As[64][40];
    __shared__ __align__(16) __bf16 Bs[64][40];
    const int wave = tid >> 6, lane = tid & 63;
    const int lm = lane & 15, kq = lane >> 4;

    f32x4 acc[4] = {};

    for (int k0 = 0; k0 < Kd; k0 += 32) {
        if (k0) __syncthreads();
        {
            const int mo = tid >> 2;
            const int ko = (tid & 3) * 8;
            if (job == 5) {
                #pragma unroll
                for (int q = 0; q < 8; ++q) {
                    const int k = ko + q;
                    As[mo][k] = (k < 24) ? (__bf16)ldin(A, (size_t)(m0 + mo) * 24 + k, bf)
                                         : (__bf16)0.f;
                }
            } else if (bf) {
                *(bf16x8*)&As[mo][ko] =
                    *(const bf16x8*)((const __bf16*)A + (size_t)(m0 + mo) * 512 + k0 + ko);
            } else {
                const float* Af = (const float*)A + (size_t)(m0 + mo) * 512 + k0 + ko;
                *(bf16x8*)&As[mo][ko] = cvt8(*(const float4*)Af, *(const float4*)(Af + 4));
            }
        }
        if (trb) {
            const int no = tid >> 2;
            const int ko = (tid & 3) * 8;
            const size_t go = (size_t)(n0 + no) * 512 + k0 + ko;
            if (bf) {
                *(bf16x8*)&Bs[no][ko] = *(const bf16x8*)((const __bf16*)Bw + go);
            } else {
                const float* Bf = (const float*)Bw + go;
                *(bf16x8*)&Bs[no][ko] = cvt8(*(const float4*)Bf, *(const float4*)(Bf + 4));
            }
        } else {
            const int kk = tid >> 3;            // 0..31
            const int nn = (tid & 7) * 8;
            if (job == 5) {
                #pragma unroll
                for (int q = 0; q < 8; ++q)
                    Bs[nn + q][kk] = (kk < 24) ? (__bf16)ldin(Bw, (size_t)kk * 512 + n0 + nn + q, bf)
                                               : (__bf16)0.f;
            } else {
                const size_t off = (size_t)(k0 + kk) * 512 + n0 + nn;
                if (bf) {
                    const bf16x8 t = *(const bf16x8*)((const __bf16*)Bw + off);
                    #pragma unroll
                    for (int q = 0; q < 8; ++q) Bs[nn + q][kk] = t[q];
                } else {
                    const float* Bf = (const float*)Bw + off;
                    #pragma unroll
                    for (int q = 0; q < 8; ++q) Bs[nn + q][kk] = (__bf16)Bf[q];
                }
            }
        }
        __syncthreads();
        const bf16x8 a = *(const bf16x8*)&As[wave * 16 + lm][kq * 8];
        #pragma unroll
        for (int nt = 0; nt < 4; ++nt) {
            const bf16x8 b = *(const bf16x8*)&Bs[nt * 16 + lm][kq * 8];
            acc[nt] = __builtin_amdgcn_mfma_f32_16x16x32_bf16(a, b, acc[nt], 0, 0, 0);
        }
    }
    // epilogue: D[m][n]: m = wave*16 + kq*4 + r2, n = nt*16 + lm
    #pragma unroll
    for (int nt = 0; nt < 4; ++nt) {
        const int n = n0 + nt * 16 + lm;
        #pragma unroll
        for (int r2 = 0; r2 < 4; ++r2) {
            const int m = m0 + wave * 16 + kq * 4 + r2;
            float v = acc[nt][r2];
            if (bias) v += ldin(bias, (size_t)n, bf);
            if (act == 1) v = gelu_f(v);
            if (act == 2) v = 1.f / (1.f + expf(-v));
            switch (job) {
                case 0: fu[(size_t)m * 512 + n] = (__bf16)v; break;
                case 5: fphi[(size_t)m * 512 + n] = (__bf16)v; break;
                case 1: fQ[(size_t)m * 512 + n] = (__bf16)v; break;
                case 3: fV[(size_t)m * 512 + n] = (__bf16)v; break;
                case 4: fG[(size_t)m * 512 + n] = (__bf16)v; break;
                case 2: {  // K transposed: [b][h][p][t]
                    const int b = m >> 10, t = m & 1023;
                    const int h = n >> 6,  p = n & 63;
                    fKT[(((size_t)b * NHEAD + h) * 64 + p) * T_SEQ + t] = (__bf16)v;
                    break;
                }
            }
        }
    }
}

// ---------------- fused uniform-task conv + attention, 4 j-tiles per block ----
// u/vphi bf16 (half staged global traffic), converted to fp32 at LDS staging.
__global__ __launch_bounds__(256) void conv_attn_k(
    const __bf16* __restrict__ u, const __bf16* __restrict__ vphi,
    float* __restrict__ w,
    const __bf16* __restrict__ Q, const __bf16* __restrict__ KT,
    const __bf16* __restrict__ V, float* __restrict__ Y)
{
    __shared__ __align__(16) unsigned char smem[49152];
    const int tid = threadIdx.x;
    const int z = blockIdx.z;
    int rem = blockIdx.x, ti = 0;
    while (rem >= ((ti + 4) >> 2)) { rem -= (ti + 4) >> 2; ++ti; }
    const int jlo = rem * 4;
    const int jhi = (jlo + 3 < ti) ? jlo + 3 : ti;
    const int t0 = ti * 64;

    if (z < 2) {
        float (*vs)[64] = (float (*)[64])smem;            // 16 KB
        float (*us)[64] = (float (*)[64])(smem + 16384);  // 32 KB
        const int rl = tid & 63, tg = tid >> 6;
        const int b = z;
        const int r0 = blockIdx.y * 64;
        const __bf16* ub = u + (size_t)b * T_SEQ * R_DIM;
        float acc[16] = {};
        for (int j = jlo; j <= jhi; ++j) {
            if (j != jlo) __syncthreads();
            const int L0 = j * 64;
            const int W0 = t0 - L0 - 63;
            #pragma unroll
            for (int jj = 0; jj < 8; ++jj) {
                const int n = jj * 256 + tid;
                const int row = n >> 4, c4 = (n & 15) * 4;
                int s = W0 + row;
                s = s < 0 ? 0 : (s > T_SEQ - 1 ? T_SEQ - 1 : s);
                const bf16x4 t = *(const bf16x4*)&ub[(size_t)s * R_DIM + r0 + c4];
                *(float4*)&us[row][c4] =
                    make_float4((float)t[0], (float)t[1], (float)t[2], (float)t[3]);
            }
            #pragma unroll
            for (int jj = 0; jj < 4; ++jj) {
                const int n = jj * 256 + tid;
                const int row = n >> 4, c4 = (n & 15) * 4;
                const bf16x4 t = *(const bf16x4*)&vphi[(size_t)(L0 + row) * R_DIM + r0 + c4];
                *(float4*)&vs[row][c4] =
                    make_float4((float)t[0], (float)t[1], (float)t[2], (float)t[3]);
            }
            __syncthreads();
            if (j < ti) {
                #pragma unroll
                for (int g = 0; g < 4; ++g) {
                    const int wsmin = tg * 16 + 49 - 16 * g;
                    float ur[30];
                    #pragma unroll
                    for (int q = 0; q < 30; ++q) ur[q] = us[wsmin + q][rl];
                    float vr[8];
                    #pragma unroll
                    for (int e = 0; e < 8; ++e) vr[e] = vs[16 * g + 2 * e][rl];
                    #pragma unroll
                    for (int e = 0; e < 8; ++e)
                        #pragma unroll
                        for (int i = 0; i < 16; ++i)
                            acc[i] += vr[e] * ur[i - 2 * e + 14];
                }
            } else {
                for (int l = 0; l < 64; l += 2) {
                    const float vv = vs[l][rl];
                    #pragma unroll
                    for (int i = 0; i < 16; ++i) {
                        const int srel = tg * 16 + i - l;
                        if (srel >= 0) acc[i] += vv * us[srel + 63][rl];
                    }
                }
            }
        }
        #pragma unroll
        for (int i = 0; i < 16; ++i)
            atomicAdd(&w[((size_t)b * T_SEQ + t0 + tg * 16 + i) * R_DIM + r0 + rl],
                      2.f * acc[i]);
    } else {
        __bf16 (*Qs)[72] = (__bf16 (*)[72])smem;
        __bf16 (*Vs)[72] = (__bf16 (*)[72])(smem + 9216);
        __bf16 (*Kt)[72] = (__bf16 (*)[72])(smem + 18432);
        __bf16 (*Sa)[72] = (__bf16 (*)[72])(smem + 27648);
        const int wave = tid >> 6, lane = tid & 63;
        const int lm = lane & 15, kq = lane >> 4;
        const int b = z - 2;
        const int h = blockIdx.y;
        const size_t cbase = ((size_t)b * T_SEQ) * D_MOD + h * HDIM;
        const __bf16* KTh = KT + (((size_t)b * NHEAD + h) * 64) * T_SEQ;
        #pragma unroll
        for (int it = 0; it < 2; ++it) {
            const int n = it * 256 + tid;
            const int row = n >> 3, p0 = (n & 7) * 8;
            *(bf16x8*)&Qs[row][p0] = *(const bf16x8*)&Q[cbase + (size_t)(t0 + row) * D_MOD + p0];
        }
        f32x4 accY[4] = {};
        for (int j = jlo; j <= jhi; ++j) {
            const int s0 = j * 64;
            __syncthreads();
            #pragma unroll
            for (int it = 0; it < 2; ++it) {
                const int n = it * 256 + tid;
                const int row = n >> 3, c0 = (n & 7) * 8;
                *(bf16x8*)&Vs[row][c0] = *(const bf16x8*)&V[cbase + (size_t)(s0 + row) * D_MOD + c0];
                *(bf16x8*)&Kt[row][c0] = *(const bf16x8*)&KTh[(size_t)row * T_SEQ + s0 + c0];
            }
            __syncthreads();
            f32x4 sacc[4] = {};
            #pragma unroll
            for (int ks = 0; ks < 2; ++ks) {
                const bf16x8 a = *(const bf16x8*)&Qs[wave * 16 + lm][ks * 32 + kq * 8];
                #pragma unroll
                for (int nt = 0; nt < 4; ++nt) {
                    const bf16x8 bb = *(const bf16x8*)&Vs[nt * 16 + lm][ks * 32 + kq * 8];
                    sacc[nt] = __builtin_amdgcn_mfma_f32_16x16x32_bf16(a, bb, sacc[nt], 0, 0, 0);
                }
            }
            const bool diag = (j == ti);
            #pragma unroll
            for (int nt = 0; nt < 4; ++nt) {
                const int sl = nt * 16 + lm;
                #pragma unroll
                for (int r2 = 0; r2 < 4; ++r2) {
                    const int tl = wave * 16 + kq * 4 + r2;
                    float v = sacc[nt][r2];
                    if (diag && sl > tl) v = 0.f;
                    Sa[tl][sl] = (__bf16)v;
                }
            }
            #pragma unroll
            for (int ks = 0; ks < 2; ++ks) {
                const bf16x8 a = *(const bf16x8*)&Sa[wave * 16 + lm][ks * 32 + kq * 8];
                #pragma unroll
                for (int nt = 0; nt < 4; ++nt) {
                    const bf16x8 bb = *(const bf16x8*)&Kt[nt * 16 + lm][ks * 32 + kq * 8];
                    accY[nt] = __builtin_amdgcn_mfma_f32_16x16x32_bf16(a, bb, accY[nt], 0, 0, 0);
                }
            }
        }
        #pragma unroll
        for (int nt = 0; nt < 4; ++nt) {
            const int nh = nt * 16 + lm;
            #pragma unroll
            for (int r2 = 0; r2 < 4; ++r2) {
                const int tl = wave * 16 + kq * 4 + r2;
                atomicAdd(&Y[cbase + (size_t)(t0 + tl) * D_MOD + nh], accY[nt][r2]);
            }
        }
    }
}

// layernorm over last dim (512): reads fp32 conv accum, writes BF16 x_tilde
__global__ __launch_bounds__(256) void ln_k(const float* __restrict__ w,
                                            __bf16* __restrict__ xt,
                                            const void* __restrict__ g,
                                            const void* __restrict__ b,
                                            const void* __restrict__ xref)
{
    const int bf = detect_bf(xref);
    const size_t row = (size_t)blockIdx.y * T_SEQ + blockIdx.x;
    const float* p = w + row * R_DIM;
    const int tid = threadIdx.x;
    const float x0 = p[tid], x1 = p[tid + 256];
    __shared__ float red[4];
    float s = x0 + x1;
    #pragma unroll
    for (int off = 32; off > 0; off >>= 1) s += __shfl_down(s, off, 64);
    if ((tid & 63) == 0) red[tid >> 6] = s;
    __syncthreads();
    const float mu = (red[0] + red[1] + red[2] + red[3]) * (1.f / 512.f);
    __syncthreads();
    const float d0 = x0 - mu, d1 = x1 - mu;
    float vsum = d0 * d0 + d1 * d1;
    #pragma unroll
    for (int off = 32; off > 0; off >>= 1) vsum += __shfl_down(vsum, off, 64);
    if ((tid & 63) == 0) red[tid >> 6] = vsum;
    __syncthreads();
    const float var = (red[0] + red[1] + red[2] + red[3]) * (1.f / 512.f);
    const float rs = rsqrtf(var + 1e-5f);
    __bf16* q = xt + row * R_DIM;
    q[tid]       = (__bf16)(d0 * rs * ldin(g, tid, bf)       + ldin(b, tid, bf));
    q[tid + 256] = (__bf16)(d1 * rs * ldin(g, tid + 256, bf) + ldin(b, tid + 256, bf));
}

// ---------------- final GEMM with fused comb: out = (g*y+(1-g)*xt) @ Wo^T + bo
// Xt bf16 (half read traffic). R15-measured pipelined 64x64 version; the
// 32x64/512-block re-tile (R16) regressed 184->188 -- keep this shape.
__global__ __launch_bounds__(256) void final_gemm(const __bf16* __restrict__ G,
                                                  const float* __restrict__ Yf,
                                                  const __bf16* __restrict__ Xt,
                                                  const void* __restrict__ Wo,
                                                  const void* __restrict__ bo,
                                                  void* __restrict__ out,
                                                  const void* __restrict__ xref)
{
    const int bf = detect_bf(xref);
    __shared__ __align__(16) __bf16 sm[2][2 * 64 * 40];
    const int tid = threadIdx.x;
    const int wave = tid >> 6, lane = tid & 63;
    const int lm = lane & 15, kq = lane >> 4;
    const int mo = tid >> 2, ko = (tid & 3) * 8;
    const int m0 = blockIdx.y * 64, n0 = blockIdx.x * 64;

    bf16x8 pg, px, pw;
    float4 py0, py1, pw0, pw1;

    auto issue = [&](int k0) {
        const size_t off = (size_t)(m0 + mo) * 512 + k0 + ko;
        pg  = *(const bf16x8*)(G + off);
        px  = *(const bf16x8*)(Xt + off);
        py0 = *(const float4*)(Yf + off); py1 = *(const float4*)(Yf + off + 4);
        const size_t ob = (size_t)(n0 + mo) * 512 + k0 + ko;
        if (bf) pw = *(const bf16x8*)((const __bf16*)Wo + ob);
        else { const float* Bf = (const float*)Wo + ob;
               pw0 = *(const float4*)Bf; pw1 = *(const float4*)(Bf + 4); }
    };
    auto commit = [&](int bi) {
        __bf16 (*As)[40] = (__bf16 (*)[40])sm[bi];
        __bf16 (*Bs)[40] = (__bf16 (*)[40])(sm[bi] + 64 * 40);
        const float yv[8] = {py0.x,py0.y,py0.z,py0.w,py1.x,py1.y,py1.z,py1.w};
        bf16x8 t;
        #pragma unroll
        for (int q = 0; q < 8; ++q) {
            const float gg = (float)pg[q];
            t[q] = (__bf16)(gg * yv[q] + (1.f - gg) * (float)px[q]);
        }
        *(bf16x8*)&As[mo][ko] = t;
        *(bf16x8*)&Bs[mo][ko] = bf ? pw : cvt8(pw0, pw1);
    };

    f32x4 acc[4] = {};
    issue(0);
    commit(0);
    __syncthreads();
    int cur = 0;
    for (int k0 = 0; k0 < 512; k0 += 32) {
        const bool haveNext = (k0 + 32 < 512);
        if (haveNext) issue(k0 + 32);
        __bf16 (*As)[40] = (__bf16 (*)[40])sm[cur];
        __bf16 (*Bs)[40] = (__bf16 (*)[40])(sm[cur] + 64 * 40);
        const bf16x8 a = *(const bf16x8*)&As[wave * 16 + lm][kq * 8];
        #pragma unroll
        for (int nt = 0; nt < 4; ++nt) {
            const bf16x8 b = *(const bf16x8*)&Bs[nt * 16 + lm][kq * 8];
            acc[nt] = __builtin_amdgcn_mfma_f32_16x16x32_bf16(a, b, acc[nt], 0, 0, 0);
        }
        if (haveNext) {
            commit(cur ^ 1);
            __syncthreads();
            cur ^= 1;
        }
    }
    #pragma unroll
    for (int nt = 0; nt < 4; ++nt) {
        const int n = n0 + nt * 16 + lm;
        #pragma unroll
        for (int r2 = 0; r2 < 4; ++r2) {
            const int m = m0 + wave * 16 + kq * 4 + r2;
            float v = acc[nt][r2] + ldin(bo, (size_t)n, bf);
            stout(out, (size_t)m * 512 + n, bf, v);
        }
    }
}

extern "C" void kernel_launch(void* const* d_in, const int* in_sizes, int n_in,
                              void* d_out, int out_size, void* d_ws, size_t ws_size,
                              hipStream_t stream)
{
    const void* x   = d_in[0];
    const void* stf = d_in[1];
    const void* Mi  = d_in[2];
    const void* Mf  = d_in[3];
    const void* Wq  = d_in[4];  const void* bq = d_in[5];
    const void* Wk  = d_in[6];  const void* bk = d_in[7];
    const void* Wv  = d_in[8];  const void* bv = d_in[9];
    const void* Wg  = d_in[10]; const void* bg = d_in[11];
    const void* Wo  = d_in[12]; const void* bo = d_in[13];
    const void* lnw = d_in[14]; const void* lnb = d_in[15];

    float* base = (float*)d_ws;
    __bf16* f_u   = (__bf16*)base;               // u bf16 (2 MB)
    __bf16* f_phi = f_u + 1048576;               // phi bf16 (1 MB)
    float*  f_w   = base + 786432;               // conv accum fp32 (4 MB, zeroed)
    float*  f_Y   = base + 1835008;              // attn accum fp32 (4 MB, zeroed)
    __bf16* f_xt  = (__bf16*)(base + 2883584);   // x_tilde bf16 (2 MB)
    __bf16* f_Q   = (__bf16*)(base + 3407872);   // bf16 2048x512 (2 MB)
    __bf16* f_KT  = f_Q + 1048576;               // bf16 K transposed [b][h][p][t]
    __bf16* f_V   = f_KT + 1048576;
    __bf16* f_G   = f_V + 1048576;
    // total ws: 21 MB

    dim3 blk(256);

    // jobs 0-5 GEMMs (64x64, BK=32), job 6 zeroes f_w+f_Y (8 MB)
    mega_gemm<<<dim3(8, 32, 7), blk, 0, stream>>>(
        x, Mi, stf, Mf, Wq, bq, Wk, bk, Wv, bv, Wg, bg,
        f_u, f_phi, f_Q, f_KT, f_V, f_G);

    conv_attn_k<<<dim3(40, 8, 4), blk, 0, stream>>>(f_u, f_phi, f_w, f_Q, f_KT, f_V, f_Y);

    ln_k<<<dim3(T_SEQ, BATCH), blk, 0, stream>>>(f_w, f_xt, lnw, lnb, x);

    final_gemm<<<dim3(8, 32), blk, 0, stream>>>(f_G, f_Y, f_xt, Wo, bo, d_out, x);
}